// Round 1
// baseline (1203.870 us; speedup 1.0000x reference)
//
#include <hip/hip_runtime.h>

// Problem constants (from reference)
#define NB     32      // B
#define NPTS   2048    // N
#define KNN    16      // K
#define FIN    32      // F_IN
#define FOUT   64      // F_OUT

// ---------------------------------------------------------------------------
// Kernel 1: exact 16-NN per point, thread-per-query.
// Distances replicate numpy fp32 arithmetic exactly (no FMA contraction):
//   sq   = ((x*x + y*y) + z*z)
//   dot  = ((qx*cx + qy*cy) + qz*cz)
//   d2   = (sq_i + sq_j) - (2*dot)
//   diagonal -> exactly 1e30 (d2_ii == 0 bitwise, + 1e30)
// Selection: sorted-insert top-16 in registers, strict '<' so ties keep the
// lower index (matches top_k tie-break). Only set membership matters (max-pool).
// ---------------------------------------------------------------------------
#define BQ 128   // queries per block; 16 blocks per batch

__global__ __launch_bounds__(BQ) void knn_kernel(
    const float* __restrict__ pos, int* __restrict__ idx_out)
{
    __shared__ float4 P[NPTS];   // 32 KB: {x, y, z, sq}
    const int b   = blockIdx.x >> 4;    // 16 blocks per batch
    const int blk = blockIdx.x & 15;
    const int t   = threadIdx.x;
    const float* pb = pos + (size_t)b * NPTS * 3;

    // Stage this batch's points + squared norms into LDS.
    for (int r = 0; r < NPTS / BQ; ++r) {
        int j = r * BQ + t;
        float px = pb[j*3 + 0];
        float py = pb[j*3 + 1];
        float pz = pb[j*3 + 2];
        float sq = __fadd_rn(__fadd_rn(__fmul_rn(px,px), __fmul_rn(py,py)),
                             __fmul_rn(pz,pz));
        P[j] = make_float4(px, py, pz, sq);
    }
    __syncthreads();

    const int q = blk * BQ + t;          // local query index in batch
    const float4 me = P[q];

    float dk[KNN]; int ik[KNN];
    #pragma unroll
    for (int s = 0; s < KNN; ++s) { dk[s] = 3.0e38f; ik[s] = 0; }

    for (int j = 0; j < NPTS; ++j) {
        float4 c = P[j];
        float dot = __fadd_rn(__fadd_rn(__fmul_rn(me.x,c.x),
                                        __fmul_rn(me.y,c.y)),
                              __fmul_rn(me.z,c.z));
        float d2 = __fsub_rn(__fadd_rn(me.w, c.w), __fmul_rn(2.0f, dot));
        if (j == q) d2 = 1e30f;          // ref: d2_ii (==0) + 1e30
        if (d2 < dk[KNN-1]) {            // guard: only insert if beats worst
            float cd = d2; int ci = j;
            #pragma unroll
            for (int s = 0; s < KNN; ++s) {
                bool sw = cd < dk[s];
                float td = dk[s]; int ti = ik[s];
                dk[s] = sw ? cd : td;  ik[s] = sw ? ci : ti;
                cd    = sw ? td : cd;  ci    = sw ? ti : ci;
            }
        }
    }

    int* o = idx_out + ((size_t)b * NPTS + q) * KNN;
    #pragma unroll
    for (int s = 0; s < KNN; ++s) o[s] = ik[s];   // local (in-batch) indices
}

// ---------------------------------------------------------------------------
// Kernel 2: fused gather + edge MLP + maxpool + skip.
// One wave per node; lane = output feature o (FOUT==64==wave).
// h_o = sum_f xi_f*(Wlo-Whi)[f][o] + sum_f xj_f*Whi[f][o] + be[o]
// edge_o = relu(max_k z_k)  (relu monotone => == max_k relu(z_k))
// out = edge + relu(x@W_nn + b_nn)
// Weight columns live in VGPRs for the whole wave; neighbor rows are staged
// per node into LDS with coalesced float4 loads, read back as ds_read_b128.
// ---------------------------------------------------------------------------
#define MLP_WAVES 4
#define NODES_PER_WAVE 16
#define LSTRIDE ((KNN + 1) * FIN)   // 17 rows of 32 floats per wave

__global__ __launch_bounds__(256) void edge_mlp_kernel(
    const float* __restrict__ x, const int* __restrict__ idxws,
    const float* __restrict__ W_edge, const float* __restrict__ b_edge,
    const float* __restrict__ W_nn, const float* __restrict__ b_nn,
    float* __restrict__ out)
{
    __shared__ float L[MLP_WAVES][LSTRIDE];
    const int lane = threadIdx.x & 63;
    const int w    = threadIdx.x >> 6;

    // Per-lane weight columns (persistent across all nodes this wave handles)
    float Wd[FIN], Whi[FIN], Wn[FIN];
    #pragma unroll
    for (int f = 0; f < FIN; ++f) {
        float lo = W_edge[f * FOUT + lane];
        float hi = W_edge[(f + FIN) * FOUT + lane];
        Whi[f] = hi;
        Wd[f]  = lo - hi;
        Wn[f]  = W_nn[f * FOUT + lane];
    }
    const float be = b_edge[lane];
    const float bn = b_nn[lane];

    float* Lw = &L[w][0];
    const int nodebase = (blockIdx.x * MLP_WAVES + w) * NODES_PER_WAVE;

    for (int it = 0; it < NODES_PER_WAVE; ++it) {
        const int n     = nodebase + it;
        const int gbase = (n >> 11) << 11;   // batch start row (global)

        int idxv = 0;
        if (lane < KNN) idxv = idxws[(size_t)n * KNN + lane];

        // Stage 16 neighbor rows (16 x 32 floats) via coalesced float4 loads.
        #pragma unroll
        for (int r = 0; r < 2; ++r) {
            int lin = r * 64 + lane;
            int k   = lin >> 3;        // neighbor 0..15
            int fq  = lin & 7;         // float4 slot 0..7
            int nb  = __shfl(idxv, k);
            const float4 v = *(const float4*)(x + ((size_t)(gbase + nb)) * FIN + fq * 4);
            *(float4*)(Lw + k * FIN + fq * 4) = v;
        }
        // Stage x_i row.
        if (lane < 8) {
            const float4 v = *(const float4*)(x + (size_t)n * FIN + lane * 4);
            *(float4*)(Lw + KNN * FIN + lane * 4) = v;
        }
        __syncthreads();   // all waves have uniform trip counts

        // base = sum xi*(Wlo-Whi), skip = sum xi*Wn  (xi broadcast from LDS)
        float base = 0.f, skip = 0.f;
        #pragma unroll
        for (int f = 0; f < FIN; ++f) {
            float xi = Lw[KNN * FIN + f];
            base = fmaf(xi, Wd[f], base);
            skip = fmaf(xi, Wn[f], skip);
        }

        float zmax = -3.0e38f;
        #pragma unroll
        for (int k = 0; k < KNN; ++k) {
            float a = 0.f;
            #pragma unroll
            for (int fq = 0; fq < 8; ++fq) {
                const float4 v = *(const float4*)(Lw + k * FIN + fq * 4);
                a = fmaf(v.x, Whi[fq*4+0], a);
                a = fmaf(v.y, Whi[fq*4+1], a);
                a = fmaf(v.z, Whi[fq*4+2], a);
                a = fmaf(v.w, Whi[fq*4+3], a);
            }
            zmax = fmaxf(zmax, a);
        }
        float edge = fmaxf(zmax + base + be, 0.f);
        float sk   = fmaxf(skip + bn, 0.f);
        out[(size_t)n * FOUT + lane] = edge + sk;

        __syncthreads();   // protect LDS against next iteration's staging
    }
}

// ---------------------------------------------------------------------------
extern "C" void kernel_launch(void* const* d_in, const int* in_sizes, int n_in,
                              void* d_out, int out_size, void* d_ws, size_t ws_size,
                              hipStream_t stream) {
    const float* x      = (const float*)d_in[0];
    const float* pos    = (const float*)d_in[1];
    const float* W_edge = (const float*)d_in[2];
    const float* b_edge = (const float*)d_in[3];
    const float* W_nn   = (const float*)d_in[4];
    const float* b_nn   = (const float*)d_in[5];
    // d_in[6] = batch (derivable: i / N), unused

    int*   idxws = (int*)d_ws;              // 32*2048*16 ints = 4 MB
    float* outp  = (float*)d_out;

    knn_kernel<<<NB * 16, BQ, 0, stream>>>(pos, idxws);
    edge_mlp_kernel<<<(NB * NPTS) / (MLP_WAVES * NODES_PER_WAVE), 256, 0, stream>>>(
        x, idxws, W_edge, b_edge, W_nn, b_nn, outp);
}

// Round 3
// 426.156 us; speedup vs baseline: 2.8250x; 2.8250x over previous
//
#include <hip/hip_runtime.h>

// Problem constants (from reference)
#define NB     32      // B
#define NPTS   2048    // N
#define KNN    16      // K
#define FIN    32      // F_IN
#define FOUT   64      // F_OUT

// ---------------------------------------------------------------------------
// Kernel 1: exact 16-NN per point.
// Block = 512 threads = 8 waves = 2 query-groups x 4 chunks.
// Each wave: lane = query (64 queries/group), scans a 512-candidate chunk.
// Pass 1: branchless values-only sorted top-16; merge 4 chunks' sorted lists
//         via LDS -> exact global 16th-smallest distance tthr per query.
// Pass 2: re-scan chunk in ascending-j order; stricts (d2<tthr) stored from
//         the front of a 16-slot list, ties (d2==tthr) from the back (both
//         j-ascending). Assembly = all stricts (chunk-ascending == j-asc),
//         then ties lowest-j-first -> exact top_k tie-break semantics.
// Distances replicate numpy fp32 arithmetic exactly (no FMA contraction).
// ---------------------------------------------------------------------------
#define CH   4              // candidate chunks
#define CHL  (NPTS / CH)    // 512 candidates per chunk
#define QG   2              // query groups per block
#define BT   (QG * CH * 64) // 512 threads

__global__ __launch_bounds__(BT) void knn_kernel(
    const float* __restrict__ pos, int* __restrict__ idx_out)
{
    __shared__ float4 P[NPTS];               // 32 KB: {x,y,z,sq}
    __shared__ float  V[QG * CH * KNN * 64]; // 32 KB, reused as int jlist
    __shared__ int    CNTS[QG * CH * 64];    // 2 KB: cntS | (cntT<<16)

    const int b   = blockIdx.x >> 4;   // 16 blocks per batch
    const int qgb = blockIdx.x & 15;   // which 128-query slab
    const int t   = threadIdx.x;
    const int w   = t >> 6;            // wave 0..7
    const int qgl = w >> 2;            // query group 0..1
    const int ch  = w & 3;             // chunk 0..3
    const int l   = t & 63;            // query lane

    const float* pb = pos + (size_t)b * NPTS * 3;

    // Stage this batch's points + squared norms into LDS (cooperative).
    for (int r = 0; r < NPTS / BT; ++r) {
        int j = r * BT + t;
        float px = pb[j*3 + 0];
        float py = pb[j*3 + 1];
        float pz = pb[j*3 + 2];
        float sq = __fadd_rn(__fadd_rn(__fmul_rn(px,px), __fmul_rn(py,py)),
                             __fmul_rn(pz,pz));
        P[j] = make_float4(px, py, pz, sq);
    }
    __syncthreads();

    const int q = (qgb * QG + qgl) * 64 + l;   // local query index in batch
    const float4 me = P[q];

    // ---- Pass 1: values-only sorted top-16 over this chunk -----------------
    float dk[KNN];
    #pragma unroll
    for (int s = 0; s < KNN; ++s) dk[s] = 1e30f;

    const int j0 = ch * CHL;
    #pragma unroll 2
    for (int jj = 0; jj < CHL; ++jj) {
        const int j = j0 + jj;
        const float4 c = P[j];
        float dot = __fadd_rn(__fadd_rn(__fmul_rn(me.x,c.x),
                                        __fmul_rn(me.y,c.y)),
                              __fmul_rn(me.z,c.z));
        float d2 = __fsub_rn(__fadd_rn(me.w, c.w), __fmul_rn(2.0f, dot));
        d2 = (j == q) ? 1e30f : d2;
        // branchless sorted insert (values only), depth-2
        float tmp[KNN];
        tmp[0] = d2;
        #pragma unroll
        for (int s = 1; s < KNN; ++s) tmp[s] = fmaxf(d2, dk[s-1]);
        #pragma unroll
        for (int s = 0; s < KNN; ++s) dk[s] = fminf(tmp[s], dk[s]);
    }

    // publish chunk-local sorted values: V[(qgl,ch,s)][lane]
    #pragma unroll
    for (int s = 0; s < KNN; ++s)
        V[((qgl * CH + ch) * KNN + s) * 64 + l] = dk[s];
    __syncthreads();

    // ---- Merge other chunks' value lists (redundant per wave) --------------
    for (int c2 = 0; c2 < CH; ++c2) {
        if (c2 == ch) continue;
        #pragma unroll
        for (int s2 = 0; s2 < KNN; ++s2) {
            float v = V[((qgl * CH + c2) * KNN + s2) * 64 + l];
            float tmp[KNN];
            tmp[0] = v;
            #pragma unroll
            for (int s = 1; s < KNN; ++s) tmp[s] = fmaxf(v, dk[s-1]);
            #pragma unroll
            for (int s = 0; s < KNN; ++s) dk[s] = fminf(tmp[s], dk[s]);
        }
    }
    const float tthr = dk[KNN-1];    // exact global 16th-smallest distance
    __syncthreads();                 // everyone done reading V before reuse

    // ---- Pass 2: recover indices; stricts from front, ties from back -------
    int* JL = (int*)V;               // jlist[(qgl,ch,slot)][lane]
    const int base = (qgl * CH + ch) * KNN * 64;
    int cntS = 0, cntT = 0;
    for (int jj = 0; jj < CHL; ++jj) {
        const int j = j0 + jj;
        const float4 c = P[j];
        float dot = __fadd_rn(__fadd_rn(__fmul_rn(me.x,c.x),
                                        __fmul_rn(me.y,c.y)),
                              __fmul_rn(me.z,c.z));
        float d2 = __fsub_rn(__fadd_rn(me.w, c.w), __fmul_rn(2.0f, dot));
        d2 = (j == q) ? 1e30f : d2;
        if (d2 <= tthr) {
            if (d2 < tthr) {
                if (cntS + cntT >= KNN) --cntT;   // evict highest-j tie
                JL[base + cntS * 64 + l] = j;
                ++cntS;                           // stricts <= 15 globally
            } else if (cntS + cntT < KNN) {
                JL[base + (KNN - 1 - cntT) * 64 + l] = j;
                ++cntT;
            }
        }
    }
    CNTS[(qgl * CH + ch) * 64 + l] = cntS | (cntT << 16);
    __syncthreads();

    // ---- Assembly: stricts (j-asc across chunks), then ties lowest-j -------
    if (ch == 0) {
        int* o = idx_out + ((size_t)b * NPTS + q) * KNN;
        int outc = 0;
        for (int c2 = 0; c2 < CH; ++c2) {
            int cs = CNTS[(qgl * CH + c2) * 64 + l] & 0xffff;
            for (int s2 = 0; s2 < cs && outc < KNN; ++s2)
                o[outc++] = JL[((qgl * CH + c2) * KNN + s2) * 64 + l];
        }
        for (int c2 = 0; c2 < CH && outc < KNN; ++c2) {
            int ct = CNTS[(qgl * CH + c2) * 64 + l] >> 16;
            for (int s2 = 0; s2 < ct && outc < KNN; ++s2)
                o[outc++] = JL[((qgl * CH + c2) * KNN + (KNN - 1 - s2)) * 64 + l];
        }
    }
}

// ---------------------------------------------------------------------------
// Kernel 2: fused gather + edge MLP + maxpool + skip.
// One wave per node; lane = output feature o (FOUT==64==wave).
// h_o = sum_f xi_f*(Wlo-Whi)[f][o] + sum_f xj_f*Whi[f][o] + be[o]
// edge_o = relu(max_k z_k)  (relu monotone => == max_k relu(z_k))
// LDS staging is wave-private -> no __syncthreads needed (compiler orders
// same-wave DS dependencies via lgkmcnt).
// ---------------------------------------------------------------------------
#define MLP_WAVES 4
#define NODES_PER_WAVE 16
#define LSTRIDE ((KNN + 1) * FIN)   // 17 rows of 32 floats per wave

__global__ __launch_bounds__(256) void edge_mlp_kernel(
    const float* __restrict__ x, const int* __restrict__ idxws,
    const float* __restrict__ W_edge, const float* __restrict__ b_edge,
    const float* __restrict__ W_nn, const float* __restrict__ b_nn,
    float* __restrict__ out)
{
    __shared__ float L[MLP_WAVES][LSTRIDE];
    const int lane = threadIdx.x & 63;
    const int w    = threadIdx.x >> 6;

    // Per-lane weight columns (persistent across all nodes this wave handles)
    float Wd[FIN], Whi[FIN], Wn[FIN];
    #pragma unroll
    for (int f = 0; f < FIN; ++f) {
        float lo = W_edge[f * FOUT + lane];
        float hi = W_edge[(f + FIN) * FOUT + lane];
        Whi[f] = hi;
        Wd[f]  = lo - hi;
        Wn[f]  = W_nn[f * FOUT + lane];
    }
    const float be = b_edge[lane];
    const float bn = b_nn[lane];

    float* Lw = &L[w][0];
    const int nodebase = (blockIdx.x * MLP_WAVES + w) * NODES_PER_WAVE;

    for (int it = 0; it < NODES_PER_WAVE; ++it) {
        const int n     = nodebase + it;
        const int gbase = (n >> 11) << 11;   // batch start row (global)

        int idxv = 0;
        if (lane < KNN) idxv = idxws[(size_t)n * KNN + lane];

        // Stage 16 neighbor rows (16 x 32 floats) via coalesced float4 loads.
        #pragma unroll
        for (int r = 0; r < 2; ++r) {
            int lin = r * 64 + lane;
            int k   = lin >> 3;        // neighbor 0..15
            int fq  = lin & 7;         // float4 slot 0..7
            int nb  = __shfl(idxv, k);
            const float4 v = *(const float4*)(x + ((size_t)(gbase + nb)) * FIN + fq * 4);
            *(float4*)(Lw + k * FIN + fq * 4) = v;
        }
        // Stage x_i row.
        if (lane < 8) {
            const float4 v = *(const float4*)(x + (size_t)n * FIN + lane * 4);
            *(float4*)(Lw + KNN * FIN + lane * 4) = v;
        }
        // no barrier: LDS region is wave-private

        // base = sum xi*(Wlo-Whi), skip = sum xi*Wn  (xi broadcast from LDS)
        float base = 0.f, skip = 0.f;
        #pragma unroll
        for (int f = 0; f < FIN; ++f) {
            float xi = Lw[KNN * FIN + f];
            base = fmaf(xi, Wd[f], base);
            skip = fmaf(xi, Wn[f], skip);
        }

        float zmax = -3.0e38f;
        #pragma unroll
        for (int k = 0; k < KNN; ++k) {
            float a = 0.f;
            #pragma unroll
            for (int fq = 0; fq < 8; ++fq) {
                const float4 v = *(const float4*)(Lw + k * FIN + fq * 4);
                a = fmaf(v.x, Whi[fq*4+0], a);
                a = fmaf(v.y, Whi[fq*4+1], a);
                a = fmaf(v.z, Whi[fq*4+2], a);
                a = fmaf(v.w, Whi[fq*4+3], a);
            }
            zmax = fmaxf(zmax, a);
        }
        float edge = fmaxf(zmax + base + be, 0.f);
        float sk   = fmaxf(skip + bn, 0.f);
        out[(size_t)n * FOUT + lane] = edge + sk;
    }
}

// ---------------------------------------------------------------------------
extern "C" void kernel_launch(void* const* d_in, const int* in_sizes, int n_in,
                              void* d_out, int out_size, void* d_ws, size_t ws_size,
                              hipStream_t stream) {
    const float* x      = (const float*)d_in[0];
    const float* pos    = (const float*)d_in[1];
    const float* W_edge = (const float*)d_in[2];
    const float* b_edge = (const float*)d_in[3];
    const float* W_nn   = (const float*)d_in[4];
    const float* b_nn   = (const float*)d_in[5];
    // d_in[6] = batch (derivable: i / N), unused

    int*   idxws = (int*)d_ws;              // 32*2048*16 ints = 4 MB
    float* outp  = (float*)d_out;

    knn_kernel<<<NB * 16, BT, 0, stream>>>(pos, idxws);
    edge_mlp_kernel<<<(NB * NPTS) / (MLP_WAVES * NODES_PER_WAVE), 256, 0, stream>>>(
        x, idxws, W_edge, b_edge, W_nn, b_nn, outp);
}

// Round 4
// 360.498 us; speedup vs baseline: 3.3395x; 1.1821x over previous
//
#include <hip/hip_runtime.h>

// Problem constants (from reference)
#define NB     32      // B
#define NPTS   2048    // N
#define KNN    16      // K
#define FIN    32      // F_IN
#define FOUT   64      // F_OUT

// ---------------------------------------------------------------------------
// Kernel 1: exact 16-NN per point.
// Block = 512 threads = 8 waves = 2 query-groups x 4 chunks.
// Each wave: lane = query (64 queries/group), scans a 512-candidate chunk.
// Pass 1: batch-8 bitonic top-16 maintenance (values only):
//   - sort 8 new distances descending (Batcher odd-even, 19 CE)
//   - bitonic split vs ascending running 16-list: dk[8+i]=min(dk[8+i],a[i])
//   - bitonic merge-16 (32 CE) -> ascending again
//   ~13.8 ops/candidate vs 31 for sequential sorted-insert.
// Merge the 4 chunks' sorted lists via LDS -> exact global 16th value tthr.
// Pass 2: re-scan chunk ascending-j; stricts (d2<tthr) from the front of a
//   16-slot list, ties (d2==tthr) from the back; assembly = stricts in j
//   order then ties lowest-j-first -> exact top_k tie-break.
// Distances replicate numpy fp32 arithmetic exactly (no FMA contraction).
// ---------------------------------------------------------------------------
#define CH   4              // candidate chunks
#define CHL  (NPTS / CH)    // 512 candidates per chunk
#define QG   2              // query groups per block
#define BT   (QG * CH * 64) // 512 threads

// compare-exchange: ascending (min at x) / descending (max at x)
#define CEA(x, y) { float _t = fminf(x, y); y = fmaxf(x, y); x = _t; }
#define CED(x, y) { float _t = fmaxf(x, y); y = fminf(x, y); x = _t; }

__global__ __launch_bounds__(BT) void knn_kernel(
    const float* __restrict__ pos, int* __restrict__ idx_out)
{
    __shared__ float4 P[NPTS];               // 32 KB: {x,y,z,sq}
    __shared__ float  V[QG * CH * KNN * 64]; // 32 KB, reused as int jlist
    __shared__ int    CNTS[QG * CH * 64];    // 2 KB: cntS | (cntT<<16)

    const int b   = blockIdx.x >> 4;   // 16 blocks per batch
    const int qgb = blockIdx.x & 15;   // which 128-query slab
    const int t   = threadIdx.x;
    const int w   = t >> 6;            // wave 0..7
    const int qgl = w >> 2;            // query group 0..1
    const int ch  = w & 3;             // chunk 0..3
    const int l   = t & 63;            // query lane

    const float* pb = pos + (size_t)b * NPTS * 3;

    // Stage this batch's points + squared norms into LDS (cooperative).
    for (int r = 0; r < NPTS / BT; ++r) {
        int j = r * BT + t;
        float px = pb[j*3 + 0];
        float py = pb[j*3 + 1];
        float pz = pb[j*3 + 2];
        float sq = __fadd_rn(__fadd_rn(__fmul_rn(px,px), __fmul_rn(py,py)),
                             __fmul_rn(pz,pz));
        P[j] = make_float4(px, py, pz, sq);
    }
    __syncthreads();

    const int q = (qgb * QG + qgl) * 64 + l;   // local query index in batch
    const float4 me = P[q];

    // ---- Pass 1: batch-8 bitonic top-16 over this chunk --------------------
    float dk[KNN];
    #pragma unroll
    for (int s = 0; s < KNN; ++s) dk[s] = 1e30f;

    const int j0 = ch * CHL;
    for (int jb = 0; jb < CHL; jb += 8) {
        float a[8];
        #pragma unroll
        for (int i = 0; i < 8; ++i) {
            const int j = j0 + jb + i;
            const float4 c = P[j];
            float dot = __fadd_rn(__fadd_rn(__fmul_rn(me.x,c.x),
                                            __fmul_rn(me.y,c.y)),
                                  __fmul_rn(me.z,c.z));
            float d2 = __fsub_rn(__fadd_rn(me.w, c.w), __fmul_rn(2.0f, dot));
            a[i] = (j == q) ? 1e30f : d2;
        }
        // Batcher odd-even sort-8, descending (19 CE)
        CED(a[0],a[1]) CED(a[2],a[3]) CED(a[4],a[5]) CED(a[6],a[7])
        CED(a[0],a[2]) CED(a[1],a[3]) CED(a[4],a[6]) CED(a[5],a[7])
        CED(a[1],a[2]) CED(a[5],a[6])
        CED(a[0],a[4]) CED(a[1],a[5]) CED(a[2],a[6]) CED(a[3],a[7])
        CED(a[2],a[4]) CED(a[3],a[5])
        CED(a[1],a[2]) CED(a[3],a[4]) CED(a[5],a[6])
        // bitonic split: keep lowest 16 of (dk asc ++ [inf x8, a desc])
        #pragma unroll
        for (int i = 0; i < 8; ++i) dk[8+i] = fminf(dk[8+i], a[i]);
        // bitonic merge-16 -> ascending (32 CE)
        CEA(dk[0],dk[8])  CEA(dk[1],dk[9])  CEA(dk[2],dk[10]) CEA(dk[3],dk[11])
        CEA(dk[4],dk[12]) CEA(dk[5],dk[13]) CEA(dk[6],dk[14]) CEA(dk[7],dk[15])
        CEA(dk[0],dk[4])  CEA(dk[1],dk[5])  CEA(dk[2],dk[6])  CEA(dk[3],dk[7])
        CEA(dk[8],dk[12]) CEA(dk[9],dk[13]) CEA(dk[10],dk[14]) CEA(dk[11],dk[15])
        CEA(dk[0],dk[2])  CEA(dk[1],dk[3])  CEA(dk[4],dk[6])  CEA(dk[5],dk[7])
        CEA(dk[8],dk[10]) CEA(dk[9],dk[11]) CEA(dk[12],dk[14]) CEA(dk[13],dk[15])
        CEA(dk[0],dk[1])  CEA(dk[2],dk[3])  CEA(dk[4],dk[5])  CEA(dk[6],dk[7])
        CEA(dk[8],dk[9])  CEA(dk[10],dk[11]) CEA(dk[12],dk[13]) CEA(dk[14],dk[15])
    }

    // publish chunk-local sorted values: V[(qgl,ch,s)][lane]
    #pragma unroll
    for (int s = 0; s < KNN; ++s)
        V[((qgl * CH + ch) * KNN + s) * 64 + l] = dk[s];
    __syncthreads();

    // ---- Merge other chunks' value lists (redundant per wave) --------------
    for (int c2 = 0; c2 < CH; ++c2) {
        if (c2 == ch) continue;
        #pragma unroll
        for (int s2 = 0; s2 < KNN; ++s2) {
            float v = V[((qgl * CH + c2) * KNN + s2) * 64 + l];
            float tmp[KNN];
            tmp[0] = v;
            #pragma unroll
            for (int s = 1; s < KNN; ++s) tmp[s] = fmaxf(v, dk[s-1]);
            #pragma unroll
            for (int s = 0; s < KNN; ++s) dk[s] = fminf(tmp[s], dk[s]);
        }
    }
    const float tthr = dk[KNN-1];    // exact global 16th-smallest distance
    __syncthreads();                 // everyone done reading V before reuse

    // ---- Pass 2: recover indices; stricts from front, ties from back -------
    int* JL = (int*)V;               // jlist[(qgl,ch,slot)][lane]
    const int base = (qgl * CH + ch) * KNN * 64;
    int cntS = 0, cntT = 0;
    for (int jj = 0; jj < CHL; ++jj) {
        const int j = j0 + jj;
        const float4 c = P[j];
        float dot = __fadd_rn(__fadd_rn(__fmul_rn(me.x,c.x),
                                        __fmul_rn(me.y,c.y)),
                              __fmul_rn(me.z,c.z));
        float d2 = __fsub_rn(__fadd_rn(me.w, c.w), __fmul_rn(2.0f, dot));
        d2 = (j == q) ? 1e30f : d2;
        if (d2 <= tthr) {
            if (d2 < tthr) {
                if (cntS + cntT >= KNN) --cntT;   // evict highest-j tie
                JL[base + cntS * 64 + l] = j;
                ++cntS;                           // stricts <= 15 globally
            } else if (cntS + cntT < KNN) {
                JL[base + (KNN - 1 - cntT) * 64 + l] = j;
                ++cntT;
            }
        }
    }
    CNTS[(qgl * CH + ch) * 64 + l] = cntS | (cntT << 16);
    __syncthreads();

    // ---- Assembly: stricts (j-asc across chunks), then ties lowest-j -------
    if (ch == 0) {
        int* o = idx_out + ((size_t)b * NPTS + q) * KNN;
        int outc = 0;
        for (int c2 = 0; c2 < CH; ++c2) {
            int cs = CNTS[(qgl * CH + c2) * 64 + l] & 0xffff;
            for (int s2 = 0; s2 < cs && outc < KNN; ++s2)
                o[outc++] = JL[((qgl * CH + c2) * KNN + s2) * 64 + l];
        }
        for (int c2 = 0; c2 < CH && outc < KNN; ++c2) {
            int ct = CNTS[(qgl * CH + c2) * 64 + l] >> 16;
            for (int s2 = 0; s2 < ct && outc < KNN; ++s2)
                o[outc++] = JL[((qgl * CH + c2) * KNN + (KNN - 1 - s2)) * 64 + l];
        }
    }
}

// ---------------------------------------------------------------------------
// Kernel 2: fused gather + edge MLP + maxpool + skip. NO LDS.
// One wave per node; lane = output feature o (FOUT==64==wave).
// Node index n is wave-uniform (readfirstlane on wave id), so the neighbor
// list and gathered x-rows have UNIFORM addresses into const __restrict__
// memory -> compiler emits s_load into SGPRs; each FMA is v_fmac(sgpr, vgpr).
// h_o = sum_f xi_f*(Wlo-Whi)[f][o] + sum_f xj_f*Whi[f][o] + be[o]
// edge_o = relu(max_k z_k)  (relu monotone)
// ---------------------------------------------------------------------------
#define MLP_WAVES 4
#define NODES_PER_WAVE 16

__global__ __launch_bounds__(256) void edge_mlp_kernel(
    const float* __restrict__ x, const int* __restrict__ idxws,
    const float* __restrict__ W_edge, const float* __restrict__ b_edge,
    const float* __restrict__ W_nn, const float* __restrict__ b_nn,
    float* __restrict__ out)
{
    const int lane = threadIdx.x & 63;
    const int w    = __builtin_amdgcn_readfirstlane(threadIdx.x >> 6); // uniform

    // Per-lane weight columns (persistent; ~96 VGPRs)
    float Wd[FIN], Whi[FIN], Wn[FIN];
    #pragma unroll
    for (int f = 0; f < FIN; ++f) {
        float lo = W_edge[f * FOUT + lane];
        float hi = W_edge[(f + FIN) * FOUT + lane];
        Whi[f] = hi;
        Wd[f]  = lo - hi;
        Wn[f]  = W_nn[f * FOUT + lane];
    }
    const float be = b_edge[lane];
    const float bn = b_nn[lane];

    const int nodebase = (blockIdx.x * MLP_WAVES + w) * NODES_PER_WAVE;

    for (int it = 0; it < NODES_PER_WAVE; ++it) {
        const int n     = nodebase + it;          // wave-uniform
        const int gbase = n & ~(NPTS - 1);        // batch start row
        const int*   __restrict__ irow = idxws + (size_t)n * KNN;
        const float* __restrict__ xi   = x + (size_t)n * FIN;

        // base = sum xi*(Wlo-Whi), skip = sum xi*Wn  (xi via scalar loads)
        float base = 0.f, skip = 0.f;
        #pragma unroll
        for (int f = 0; f < FIN; ++f) {
            float v = xi[f];                      // uniform -> SGPR
            base = fmaf(v, Wd[f], base);
            skip = fmaf(v, Wn[f], skip);
        }

        float zmax = -3.0e38f;
        #pragma unroll
        for (int k = 0; k < KNN; ++k) {
            const float* __restrict__ row = x + (size_t)(gbase + irow[k]) * FIN;
            float acc = 0.f;
            #pragma unroll
            for (int f = 0; f < FIN; ++f)
                acc = fmaf(row[f], Whi[f], acc);  // s_load operand x vgpr
            zmax = fmaxf(zmax, acc);
        }
        out[(size_t)n * FOUT + lane] =
            fmaxf(zmax + base + be, 0.f) + fmaxf(skip + bn, 0.f);
    }
}

// ---------------------------------------------------------------------------
extern "C" void kernel_launch(void* const* d_in, const int* in_sizes, int n_in,
                              void* d_out, int out_size, void* d_ws, size_t ws_size,
                              hipStream_t stream) {
    const float* x      = (const float*)d_in[0];
    const float* pos    = (const float*)d_in[1];
    const float* W_edge = (const float*)d_in[2];
    const float* b_edge = (const float*)d_in[3];
    const float* W_nn   = (const float*)d_in[4];
    const float* b_nn   = (const float*)d_in[5];
    // d_in[6] = batch (derivable: i / N), unused

    int*   idxws = (int*)d_ws;              // 32*2048*16 ints = 4 MB
    float* outp  = (float*)d_out;

    knn_kernel<<<NB * 16, BT, 0, stream>>>(pos, idxws);
    edge_mlp_kernel<<<(NB * NPTS) / (MLP_WAVES * NODES_PER_WAVE), 256, 0, stream>>>(
        x, idxws, W_edge, b_edge, W_nn, b_nn, outp);
}

// Round 5
// 247.699 us; speedup vs baseline: 4.8602x; 1.4554x over previous
//
#include <hip/hip_runtime.h>

// Problem constants (from reference)
#define NB     32      // B
#define NPTS   2048    // N
#define KNN    16      // K
#define FIN    32      // F_IN
#define FOUT   64      // F_OUT

typedef __attribute__((ext_vector_type(8))) short bf16x8;
typedef __attribute__((ext_vector_type(4))) float f32x4;

// RNE float->bf16 pack (exact match of __float2bfloat16 for finite inputs)
__device__ inline unsigned bf16pk(float lo, float hi) {
    unsigned a = __float_as_uint(lo), b = __float_as_uint(hi);
    a = (a + 0x7fffu + ((a >> 16) & 1u)) >> 16;
    b = (b + 0x7fffu + ((b >> 16) & 1u)) >> 16;
    return (a & 0xffffu) | (b << 16);
}

// ---------------------------------------------------------------------------
// Kernel 1: exact 16-NN per point (structure as R4, passed bitwise).
// Only change: chunk-merge now bitonic reverse-min + merge-16 network
// (~80 instr/chunk vs ~500 for sequential insert).
// ---------------------------------------------------------------------------
#define CH   4
#define CHL  (NPTS / CH)
#define QG   2
#define BT   (QG * CH * 64)

#define CEA(x, y) { float _t = fminf(x, y); y = fmaxf(x, y); x = _t; }
#define CED(x, y) { float _t = fmaxf(x, y); y = fminf(x, y); x = _t; }

// sorts a bitonic 16-sequence ascending (distances 8,4,2,1)
#define BMERGE16(dk) \
    CEA(dk[0],dk[8])  CEA(dk[1],dk[9])  CEA(dk[2],dk[10]) CEA(dk[3],dk[11]) \
    CEA(dk[4],dk[12]) CEA(dk[5],dk[13]) CEA(dk[6],dk[14]) CEA(dk[7],dk[15]) \
    CEA(dk[0],dk[4])  CEA(dk[1],dk[5])  CEA(dk[2],dk[6])  CEA(dk[3],dk[7])  \
    CEA(dk[8],dk[12]) CEA(dk[9],dk[13]) CEA(dk[10],dk[14]) CEA(dk[11],dk[15]) \
    CEA(dk[0],dk[2])  CEA(dk[1],dk[3])  CEA(dk[4],dk[6])  CEA(dk[5],dk[7])  \
    CEA(dk[8],dk[10]) CEA(dk[9],dk[11]) CEA(dk[12],dk[14]) CEA(dk[13],dk[15]) \
    CEA(dk[0],dk[1])  CEA(dk[2],dk[3])  CEA(dk[4],dk[5])  CEA(dk[6],dk[7])  \
    CEA(dk[8],dk[9])  CEA(dk[10],dk[11]) CEA(dk[12],dk[13]) CEA(dk[14],dk[15])

__global__ __launch_bounds__(BT) void knn_kernel(
    const float* __restrict__ pos, int* __restrict__ idx_out)
{
    __shared__ float4 P[NPTS];
    __shared__ float  V[QG * CH * KNN * 64];
    __shared__ int    CNTS[QG * CH * 64];

    const int b   = blockIdx.x >> 4;
    const int qgb = blockIdx.x & 15;
    const int t   = threadIdx.x;
    const int w   = t >> 6;
    const int qgl = w >> 2;
    const int ch  = w & 3;
    const int l   = t & 63;

    const float* pb = pos + (size_t)b * NPTS * 3;

    for (int r = 0; r < NPTS / BT; ++r) {
        int j = r * BT + t;
        float px = pb[j*3 + 0];
        float py = pb[j*3 + 1];
        float pz = pb[j*3 + 2];
        float sq = __fadd_rn(__fadd_rn(__fmul_rn(px,px), __fmul_rn(py,py)),
                             __fmul_rn(pz,pz));
        P[j] = make_float4(px, py, pz, sq);
    }
    __syncthreads();

    const int q = (qgb * QG + qgl) * 64 + l;
    const float4 me = P[q];

    float dk[KNN];
    #pragma unroll
    for (int s = 0; s < KNN; ++s) dk[s] = 1e30f;

    const int j0 = ch * CHL;
    for (int jb = 0; jb < CHL; jb += 8) {
        float a[8];
        #pragma unroll
        for (int i = 0; i < 8; ++i) {
            const int j = j0 + jb + i;
            const float4 c = P[j];
            float dot = __fadd_rn(__fadd_rn(__fmul_rn(me.x,c.x),
                                            __fmul_rn(me.y,c.y)),
                                  __fmul_rn(me.z,c.z));
            float d2 = __fsub_rn(__fadd_rn(me.w, c.w), __fmul_rn(2.0f, dot));
            a[i] = (j == q) ? 1e30f : d2;
        }
        // Batcher odd-even sort-8, descending (19 CE)
        CED(a[0],a[1]) CED(a[2],a[3]) CED(a[4],a[5]) CED(a[6],a[7])
        CED(a[0],a[2]) CED(a[1],a[3]) CED(a[4],a[6]) CED(a[5],a[7])
        CED(a[1],a[2]) CED(a[5],a[6])
        CED(a[0],a[4]) CED(a[1],a[5]) CED(a[2],a[6]) CED(a[3],a[7])
        CED(a[2],a[4]) CED(a[3],a[5])
        CED(a[1],a[2]) CED(a[3],a[4]) CED(a[5],a[6])
        #pragma unroll
        for (int i = 0; i < 8; ++i) dk[8+i] = fminf(dk[8+i], a[i]);
        BMERGE16(dk)
    }

    #pragma unroll
    for (int s = 0; s < KNN; ++s)
        V[((qgl * CH + ch) * KNN + s) * 64 + l] = dk[s];
    __syncthreads();

    // bitonic chunk-merge: reverse-min + merge-16 per other chunk
    for (int c2 = 0; c2 < CH; ++c2) {
        if (c2 == ch) continue;
        float v[KNN];
        #pragma unroll
        for (int s2 = 0; s2 < KNN; ++s2)
            v[s2] = V[((qgl * CH + c2) * KNN + s2) * 64 + l];
        #pragma unroll
        for (int s = 0; s < KNN; ++s) dk[s] = fminf(dk[s], v[KNN-1-s]);
        BMERGE16(dk)
    }
    const float tthr = dk[KNN-1];
    __syncthreads();

    int* JL = (int*)V;
    const int base = (qgl * CH + ch) * KNN * 64;
    int cntS = 0, cntT = 0;
    for (int jj = 0; jj < CHL; ++jj) {
        const int j = j0 + jj;
        const float4 c = P[j];
        float dot = __fadd_rn(__fadd_rn(__fmul_rn(me.x,c.x),
                                        __fmul_rn(me.y,c.y)),
                              __fmul_rn(me.z,c.z));
        float d2 = __fsub_rn(__fadd_rn(me.w, c.w), __fmul_rn(2.0f, dot));
        d2 = (j == q) ? 1e30f : d2;
        if (d2 <= tthr) {
            if (d2 < tthr) {
                if (cntS + cntT >= KNN) --cntT;
                JL[base + cntS * 64 + l] = j;
                ++cntS;
            } else if (cntS + cntT < KNN) {
                JL[base + (KNN - 1 - cntT) * 64 + l] = j;
                ++cntT;
            }
        }
    }
    CNTS[(qgl * CH + ch) * 64 + l] = cntS | (cntT << 16);
    __syncthreads();

    if (ch == 0) {
        int* o = idx_out + ((size_t)b * NPTS + q) * KNN;
        int outc = 0;
        for (int c2 = 0; c2 < CH; ++c2) {
            int cs = CNTS[(qgl * CH + c2) * 64 + l] & 0xffff;
            for (int s2 = 0; s2 < cs && outc < KNN; ++s2)
                o[outc++] = JL[((qgl * CH + c2) * KNN + s2) * 64 + l];
        }
        for (int c2 = 0; c2 < CH && outc < KNN; ++c2) {
            int ct = CNTS[(qgl * CH + c2) * 64 + l] >> 16;
            for (int s2 = 0; s2 < ct && outc < KNN; ++s2)
                o[outc++] = JL[((qgl * CH + c2) * KNN + (KNN - 1 - s2)) * 64 + l];
        }
    }
}

// ---------------------------------------------------------------------------
// Kernel 2: MFMA edge MLP. One wave per 16-node tile.
//  - Phase 1: stage the 16 nodes' own x_i rows (fp32->bf16) into a wave-
//    private LDS A-tile, 1 MFMA x4 frags with B=Wd -> base, x4 with Wn -> skip
//    (D layout: col=lane&15 (+16f), node=(lane>>4)*4+reg).
//  - Phase 2 (per node): gather 16 neighbor rows -> bf16 A-tile ->
//    4x mfma_f32_16x16x32_bf16 with B=Whi -> max over 16 rows
//    (intra-lane fmax + shfl_xor 16/32) -> zbuf[node][col] in LDS.
//  - Phase 3: out = relu(zmax+base+be) + relu(skip+bn), D-layout stores.
// A-tile row stride 80 B -> 2-way LDS aliasing max (free per m136).
// All LDS is wave-private: zero __syncthreads.
// ---------------------------------------------------------------------------
#define MLP_WAVES 4
#define AROW 20                        // A-tile row stride in dwords (80 B)
#define AWORDS (16 * AROW)             // 320 dwords
#define ZROW 65                        // zbuf row stride in floats
#define ZWORDS (16 * ZROW)             // 1040 dwords

__global__ __launch_bounds__(256) void edge_mlp_kernel(
    const float* __restrict__ x, const int* __restrict__ idxws,
    const float* __restrict__ W_edge, const float* __restrict__ b_edge,
    const float* __restrict__ W_nn, const float* __restrict__ b_nn,
    float* __restrict__ out)
{
    __shared__ unsigned Abuf[MLP_WAVES][AWORDS];
    __shared__ float    Zbuf[MLP_WAVES][ZWORDS];

    const int lane = threadIdx.x & 63;
    const int w    = threadIdx.x >> 6;
    const int c15  = lane & 15;        // frag col within 16
    const int g    = lane >> 4;        // quad group 0..3
    const int r4   = lane >> 2;        // staging row 0..15
    const int q4   = lane & 3;         // staging feature-chunk 0..3

    unsigned* Aw = &Abuf[w][0];
    float*    Zw = &Zbuf[w][0];

    // ---- One-time: B-fragments (bf16) and per-lane epilogue constants ------
    // B-frag (BT-style): lane holds col n=16f+c15, k=(g*8+j), j=0..7.
    int4 Bhi[4], Bd[4], Bn[4];
    #pragma unroll
    for (int f = 0; f < 4; ++f) {
        const int col = 16 * f + c15;
        unsigned ph[4], pd[4], pn[4];
        #pragma unroll
        for (int d = 0; d < 4; ++d) {
            const int k0 = g * 8 + 2 * d;
            float h0 = W_edge[(FIN + k0)     * FOUT + col];
            float h1 = W_edge[(FIN + k0 + 1) * FOUT + col];
            float l0 = W_edge[k0       * FOUT + col] - h0;
            float l1 = W_edge[(k0 + 1) * FOUT + col] - h1;
            float n0 = W_nn[k0       * FOUT + col];
            float n1 = W_nn[(k0 + 1) * FOUT + col];
            ph[d] = bf16pk(h0, h1);
            pd[d] = bf16pk(l0, l1);
            pn[d] = bf16pk(n0, n1);
        }
        Bhi[f] = make_int4(ph[0], ph[1], ph[2], ph[3]);
        Bd[f]  = make_int4(pd[0], pd[1], pd[2], pd[3]);
        Bn[f]  = make_int4(pn[0], pn[1], pn[2], pn[3]);
    }
    float beF[4], bnF[4];
    #pragma unroll
    for (int f = 0; f < 4; ++f) {
        beF[f] = b_edge[16 * f + c15];
        bnF[f] = b_nn[16 * f + c15];
    }

    const int tile  = blockIdx.x * MLP_WAVES + w;   // 16-node tile index
    const int n0    = tile * 16;
    const int gbase = n0 & ~(NPTS - 1);             // batch start row

    const f32x4 zf = {0.f, 0.f, 0.f, 0.f};

    // ---- Phase 1: base/skip via MFMA over the 16 x_i rows ------------------
    {
        const float* rp = x + (size_t)(n0 + r4) * FIN + q4 * 8;
        float4 v0 = *(const float4*)rp;
        float4 v1 = *(const float4*)(rp + 4);
        int4 pk = make_int4(bf16pk(v0.x, v0.y), bf16pk(v0.z, v0.w),
                            bf16pk(v1.x, v1.y), bf16pk(v1.z, v1.w));
        *(int4*)(Aw + r4 * AROW + q4 * 4) = pk;
    }
    bf16x8 afi = *(bf16x8*)(Aw + c15 * AROW + g * 4);
    f32x4 baseF[4], skipF[4];
    #pragma unroll
    for (int f = 0; f < 4; ++f) {
        baseF[f] = __builtin_amdgcn_mfma_f32_16x16x32_bf16(
            afi, *(bf16x8*)&Bd[f], zf, 0, 0, 0);
        skipF[f] = __builtin_amdgcn_mfma_f32_16x16x32_bf16(
            afi, *(bf16x8*)&Bn[f], zf, 0, 0, 0);
    }

    // ---- Phase 2: per node, gather + MFMA + row-max ------------------------
    for (int i = 0; i < 16; ++i) {
        const int n  = n0 + i;
        const int nb = idxws[(size_t)n * KNN + r4];   // neighbor for my row
        const float* rp = x + (size_t)(gbase + nb) * FIN + q4 * 8;
        float4 v0 = *(const float4*)rp;
        float4 v1 = *(const float4*)(rp + 4);
        int4 pk = make_int4(bf16pk(v0.x, v0.y), bf16pk(v0.z, v0.w),
                            bf16pk(v1.x, v1.y), bf16pk(v1.z, v1.w));
        *(int4*)(Aw + r4 * AROW + q4 * 4) = pk;

        bf16x8 af = *(bf16x8*)(Aw + c15 * AROW + g * 4);

        float rmax[4];
        #pragma unroll
        for (int f = 0; f < 4; ++f) {
            f32x4 z = __builtin_amdgcn_mfma_f32_16x16x32_bf16(
                af, *(bf16x8*)&Bhi[f], zf, 0, 0, 0);
            float m = fmaxf(fmaxf(z[0], z[1]), fmaxf(z[2], z[3]));
            m = fmaxf(m, __shfl_xor(m, 16));
            m = fmaxf(m, __shfl_xor(m, 32));
            rmax[f] = m;                 // max over all 16 rows, col 16f+c15
        }
        // my output col for this node: 16*g + c15  -> pick frag g
        float zv = (g == 0) ? rmax[0] : (g == 1) ? rmax[1]
                 : (g == 2) ? rmax[2] : rmax[3];
        Zw[i * ZROW + 16 * g + c15] = zv;
    }

    // ---- Phase 3: epilogue + store (D layout: node=(g*4+reg), col=16f+c15) -
    #pragma unroll
    for (int f = 0; f < 4; ++f) {
        #pragma unroll
        for (int reg = 0; reg < 4; ++reg) {
            const int nd = g * 4 + reg;
            float zmax = Zw[nd * ZROW + 16 * f + c15];
            float e  = fmaxf(zmax + baseF[f][reg] + beF[f], 0.f);
            float sk = fmaxf(skipF[f][reg] + bnF[f], 0.f);
            out[(size_t)(n0 + nd) * FOUT + 16 * f + c15] = e + sk;
        }
    }
}

// ---------------------------------------------------------------------------
extern "C" void kernel_launch(void* const* d_in, const int* in_sizes, int n_in,
                              void* d_out, int out_size, void* d_ws, size_t ws_size,
                              hipStream_t stream) {
    const float* x      = (const float*)d_in[0];
    const float* pos    = (const float*)d_in[1];
    const float* W_edge = (const float*)d_in[2];
    const float* b_edge = (const float*)d_in[3];
    const float* W_nn   = (const float*)d_in[4];
    const float* b_nn   = (const float*)d_in[5];

    int*   idxws = (int*)d_ws;              // 32*2048*16 ints = 4 MB
    float* outp  = (float*)d_out;

    knn_kernel<<<NB * 16, BT, 0, stream>>>(pos, idxws);
    edge_mlp_kernel<<<(NB * NPTS) / (MLP_WAVES * 16), 256, 0, stream>>>(
        x, idxws, W_edge, b_edge, W_nn, b_nn, outp);
}